// Round 4
// baseline (177.406 us; speedup 1.0000x reference)
//
#include <hip/hip_runtime.h>

#define HW 128

typedef __attribute__((ext_vector_type(8))) short  bfrag;   // 8 bf16 (4 VGPRs)
typedef __attribute__((ext_vector_type(16))) float f16x;    // 32x32 accumulator

__device__ __forceinline__ float lrelu(float x) { return x > 0.f ? x : 0.1f * x; }

// RNE fp32 -> bf16 (bit-level, no header dependency)
__device__ __forceinline__ short f2bf(float f) {
    unsigned u = __builtin_bit_cast(unsigned, f);
    u = u + 0x7FFFu + ((u >> 16) & 1u);
    return (short)(u >> 16);
}
__device__ __forceinline__ float bf2f(short s) {
    return __builtin_bit_cast(float, (unsigned)(unsigned short)s << 16);
}

__device__ float g_kern[32 * 64 * 12];            // [b][c][12] att-folded kernels (9 used)
__device__ short g_whi[64 * 64], g_wlo[64 * 64];  // conv_w bf16 hi/lo, [o][c]

// ---------- prep: b<32 -> att-folded depthwise kernels; b==32 -> W hi/lo split ----------
__global__ __launch_bounds__(64) void dgfem_prep(
    const float* __restrict__ v, const float* __restrict__ ca_w1,
    const float* __restrict__ ca_w2, const float* __restrict__ k_w1,
    const float* __restrict__ k_w2, const float* __restrict__ conv_w)
{
    const int b = blockIdx.x;
    const int t = threadIdx.x;           // 64 threads

    if (b == 32) {                       // bf16 hi/lo decomposition of conv_w
        for (int i = t; i < 4096; i += 64) {
            float wv = conv_w[i];
            short hi = f2bf(wv);
            short lo = f2bf(wv - bf2f(hi));
            g_whi[i] = hi;               // i = o*64 + c  (row o, contiguous c)
            g_wlo[i] = lo;
        }
        return;
    }

    __shared__ float vb[64], t1[8], att[64], t2[64];
    vb[t] = v[b * 64 + t];
    __syncthreads();

    if (t < 8) {
        float s = 0.f;
        for (int j = 0; j < 64; ++j) s += vb[j] * ca_w1[t * 64 + j];
        t1[t] = lrelu(s);
    }
    {
        float s = 0.f;
        for (int j = 0; j < 64; ++j) s += vb[j] * k_w1[t * 64 + j];
        t2[t] = lrelu(s);
    }
    __syncthreads();
    {
        float s = 0.f;
        for (int i = 0; i < 8; ++i) s += t1[i] * ca_w2[t * 8 + i];
        att[t] = 1.f / (1.f + expf(-s));
    }
    __syncthreads();
    // fold att[c] into kernel (conv(x*a,k) == conv(x,a*k)); padded stride 12
    for (int r = t; r < 576; r += 64) {
        int c = r / 9, tp = r - c * 9;
        float s = 0.f;
        for (int j = 0; j < 64; ++j) s += t2[j] * k_w2[r * 64 + j];
        g_kern[b * 768 + c * 12 + tp] = s * att[c];
    }
}

// ---- fused: depthwise 3x3 (direct global) + lrelu + 1x1 conv via bf16-split MFMA ----
__global__ __launch_bounds__(256) void dgfem_main(
    const float* __restrict__ x0, const float* __restrict__ conv_b,
    float* __restrict__ out)
{
    const int t  = threadIdx.x;
    const int w  = t >> 6;               // wave = px n-tile (0..3)
    const int l  = t & 63;
    const int g  = l >> 5;               // k-half of the wave
    const int ln = l & 31;               // col / A-row within 32x32 tile

    // XCD-aware swizzle: XCD k gets contiguous rows of batches 4k..4k+3
    const int bid  = blockIdx.x;                 // 0..4095
    const int orig = (bid & 7) * 512 + (bid >> 3);
    const int b    = orig >> 7;                  // 0..31
    const int gy   = orig & 127;                 // output row
    const int px   = w * 32 + ln;                // 0..127

    // stencil geometry: clamped offsets + float masks (lane-constant)
    int   off[9];
    float mskf[9];
    #pragma unroll
    for (int dy = 0; dy < 3; ++dy) {
        int yi = gy + dy - 1;
        bool my = (unsigned)yi < HW;
        int cy = my ? yi : 0;
        #pragma unroll
        for (int dx = 0; dx < 3; ++dx) {
            int xi = px + dx - 1;
            bool mx = (unsigned)xi < HW;
            int cx = mx ? xi : 0;
            off[dy * 3 + dx]  = cy * HW + cx;
            mskf[dy * 3 + dx] = (my && mx) ? 1.f : 0.f;
        }
    }

    const float* xb = x0 + ((size_t)b << 20);    // b * 64 * 16384
    const float* kb = g_kern + b * 768;

    f16x acc0, acc1;
    #pragma unroll
    for (int i = 0; i < 16; ++i) { acc0[i] = 0.f; acc1[i] = 0.f; }

    #pragma unroll 1
    for (int s = 0; s < 4; ++s) {
        // ---- compute this lane's 8 B-fragment y values (c = s*16 + g*8 + j) ----
        float yv[8];
        #pragma unroll
        for (int j = 0; j < 8; ++j) {
            const int c = s * 16 + g * 8 + j;
            const float* xc = xb + (c << 14);
            const float* kc = kb + c * 12;
            float4 kA = *(const float4*)kc;
            float4 kB = *(const float4*)(kc + 4);
            float  k8 = kc[8];
            float a = 0.f;
            a += kA.x * (mskf[0] * xc[off[0]]);
            a += kA.y * (mskf[1] * xc[off[1]]);
            a += kA.z * (mskf[2] * xc[off[2]]);
            a += kA.w * (mskf[3] * xc[off[3]]);
            a += kB.x * (mskf[4] * xc[off[4]]);
            a += kB.y * (mskf[5] * xc[off[5]]);
            a += kB.z * (mskf[6] * xc[off[6]]);
            a += kB.w * (mskf[7] * xc[off[7]]);
            a += k8   * (mskf[8] * xc[off[8]]);
            yv[j] = lrelu(a);
        }
        // ---- hi/lo bf16 split of y ----
        bfrag yhi, ylo;
        #pragma unroll
        for (int j = 0; j < 8; ++j) {
            short h = f2bf(yv[j]);
            yhi[j] = h;
            ylo[j] = f2bf(yv[j] - bf2f(h));
        }
        // ---- A fragments (W rows; same (g,j)->k map as B so any k-perm cancels) ----
        const int coff = s * 16 + g * 8;
        bfrag whi0 = *(const bfrag*)(g_whi + (ln << 6) + coff);
        bfrag whi1 = *(const bfrag*)(g_whi + ((32 + ln) << 6) + coff);
        bfrag wlo0 = *(const bfrag*)(g_wlo + (ln << 6) + coff);
        bfrag wlo1 = *(const bfrag*)(g_wlo + ((32 + ln) << 6) + coff);

        acc0 = __builtin_amdgcn_mfma_f32_32x32x16_bf16(whi0, yhi, acc0, 0, 0, 0);
        acc0 = __builtin_amdgcn_mfma_f32_32x32x16_bf16(whi0, ylo, acc0, 0, 0, 0);
        acc0 = __builtin_amdgcn_mfma_f32_32x32x16_bf16(wlo0, yhi, acc0, 0, 0, 0);
        acc1 = __builtin_amdgcn_mfma_f32_32x32x16_bf16(whi1, yhi, acc1, 0, 0, 0);
        acc1 = __builtin_amdgcn_mfma_f32_32x32x16_bf16(whi1, ylo, acc1, 0, 0, 0);
        acc1 = __builtin_amdgcn_mfma_f32_32x32x16_bf16(wlo1, yhi, acc1, 0, 0, 0);
    }

    // ---- epilogue: D layout col=lane&31, row=(reg&3)+8*(reg>>2)+4*(lane>>5) ----
    float* ob = out + ((size_t)b << 20) + gy * HW + px;
    #pragma unroll
    for (int q = 0; q < 4; ++q) {
        const int obase = 8 * q + 4 * g;
        float4 b0 = *(const float4*)&conv_b[obase];
        float4 b1 = *(const float4*)&conv_b[32 + obase];
        const float* b0f = (const float*)&b0;
        const float* b1f = (const float*)&b1;
        #pragma unroll
        for (int rr = 0; rr < 4; ++rr) {
            ob[(size_t)(obase + rr) * 16384]      = acc0[q * 4 + rr] + b0f[rr];
            ob[(size_t)(32 + obase + rr) * 16384] = acc1[q * 4 + rr] + b1f[rr];
        }
    }
}

extern "C" void kernel_launch(void* const* d_in, const int* in_sizes, int n_in,
                              void* d_out, int out_size, void* d_ws, size_t ws_size,
                              hipStream_t stream) {
    const float* x0     = (const float*)d_in[0];
    const float* v      = (const float*)d_in[1];
    const float* ca_w1  = (const float*)d_in[2];
    const float* ca_w2  = (const float*)d_in[3];
    const float* k_w1   = (const float*)d_in[4];
    const float* k_w2   = (const float*)d_in[5];
    const float* conv_w = (const float*)d_in[6];
    const float* conv_b = (const float*)d_in[7];
    float* outp = (float*)d_out;

    dgfem_prep<<<dim3(33), dim3(64), 0, stream>>>(v, ca_w1, ca_w2, k_w1, k_w2, conv_w);
    dgfem_main<<<dim3(4096), dim3(256), 0, stream>>>(x0, conv_b, outp);
}

// Round 5
// 164.523 us; speedup vs baseline: 1.0783x; 1.0783x over previous
//
#include <hip/hip_runtime.h>

#define HW 128

typedef __attribute__((ext_vector_type(8))) short  bfrag;   // 8 bf16 (4 VGPRs)
typedef __attribute__((ext_vector_type(16))) float f16x;    // 32x32 accumulator

__device__ __forceinline__ float lrelu(float x) { return x > 0.f ? x : 0.1f * x; }

// RNE fp32 -> bf16 (prep only)
__device__ __forceinline__ short f2bf(float f) {
    unsigned u = __builtin_bit_cast(unsigned, f);
    u = u + 0x7FFFu + ((u >> 16) & 1u);
    return (short)(u >> 16);
}
__device__ __forceinline__ float bf2f(short s) {
    return __builtin_bit_cast(float, (unsigned)(unsigned short)s << 16);
}

// [b][(s*8+j)*20 + tap*2 + g] : att-folded depthwise taps, half-wave-paired
__device__ float g_kpair[32 * 640];
__device__ short g_whi[4096], g_wlo[4096];        // conv_w bf16 hi/lo, [o*64+c]

// ---------- prep: b<32 -> att-folded kernels (paired layout); b==32 -> W split ----------
__global__ __launch_bounds__(64) void dgfem_prep(
    const float* __restrict__ v, const float* __restrict__ ca_w1,
    const float* __restrict__ ca_w2, const float* __restrict__ k_w1,
    const float* __restrict__ k_w2, const float* __restrict__ conv_w)
{
    const int b = blockIdx.x;
    const int t = threadIdx.x;           // 64 threads

    if (b == 32) {                       // bf16 hi/lo decomposition of conv_w
        for (int i = t; i < 4096; i += 64) {
            float wv = conv_w[i];
            short hi = f2bf(wv);
            short lo = f2bf(wv - bf2f(hi));
            g_whi[i] = hi;
            g_wlo[i] = lo;
        }
        return;
    }

    __shared__ float vb[64], t1[8], att[64], t2[64];
    vb[t] = v[b * 64 + t];
    __syncthreads();

    if (t < 8) {
        float s = 0.f;
        for (int j = 0; j < 64; ++j) s += vb[j] * ca_w1[t * 64 + j];
        t1[t] = lrelu(s);
    }
    {
        float s = 0.f;
        for (int j = 0; j < 64; ++j) s += vb[j] * k_w1[t * 64 + j];
        t2[t] = lrelu(s);
    }
    __syncthreads();
    {
        float s = 0.f;
        for (int i = 0; i < 8; ++i) s += t1[i] * ca_w2[t * 8 + i];
        att[t] = 1.f / (1.f + expf(-s));
    }
    __syncthreads();
    // fold att[c] into kernel (conv(x*a,k) == conv(x,a*k)); paired layout
    for (int r = t; r < 576; r += 64) {
        int c = r / 9, tp = r - c * 9;
        float s = 0.f;
        for (int j = 0; j < 64; ++j) s += t2[j] * k_w2[r * 64 + j];
        int ss = c >> 4, gg = (c >> 3) & 1, jj = c & 7;
        g_kpair[b * 640 + (ss * 8 + jj) * 20 + tp * 2 + gg] = s * att[c];
    }
}

// ---- fused: depthwise 3x3 (direct global, zero-VALU addr) + 1x1 via bf16-split MFMA ----
__global__ __launch_bounds__(256, 4) void dgfem_main(
    const float* __restrict__ x0, const float* __restrict__ conv_b,
    float* __restrict__ out)
{
    const int t  = threadIdx.x;
    const int w  = t >> 6;               // wave = px col-tile (0..3)
    const int l  = t & 63;
    const int g  = l >> 5;               // k-half of the wave
    const int ln = l & 31;               // col / A-row within 32x32 tile

    // XCD-aware swizzle: XCD k gets contiguous rows of batches 4k..4k+3
    const int bid  = blockIdx.x;                 // 0..4095
    const int orig = (bid & 7) * 512 + (bid >> 3);
    const int b    = orig >> 7;                  // 0..31
    const int gy   = orig & 127;                 // output row
    const int px   = w * 32 + ln;                // 0..127

    __shared__ float kls[640];                   // this b's paired kernel table
    for (int i = t; i < 640; i += 256) kls[i] = g_kpair[b * 640 + i];

    // per-lane BYTE offsets (incl. g-part: g*8 channels = 524288 B) + masks
    int   offb[9];
    float mskf[9];
    #pragma unroll
    for (int dy = 0; dy < 3; ++dy) {
        int yi = gy + dy - 1;
        bool my = (unsigned)yi < HW;
        int cy = my ? yi : 0;
        #pragma unroll
        for (int dx = 0; dx < 3; ++dx) {
            int xi = px + dx - 1;
            bool mx = (unsigned)xi < HW;
            int cx = mx ? xi : 0;
            offb[dy * 3 + dx] = (g * 131072 + cy * HW + cx) * 4;
            mskf[dy * 3 + dx] = (my && mx) ? 1.f : 0.f;
        }
    }
    const int woffb = ln * 128 + g * 16;         // W-row byte offset (o-tile 0)

    const char* xb  = (const char*)(x0 + ((size_t)b << 20));
    const char* klb = (const char*)kls + g * 4;
    __syncthreads();

    f16x acc0, acc1;
    #pragma unroll
    for (int i = 0; i < 16; ++i) { acc0[i] = 0.f; acc1[i] = 0.f; }

    #pragma unroll 1
    for (int s = 0; s < 4; ++s) {
        bfrag yhi, ylo;
        const char* xs_ = xb + (size_t)s * (16 * 65536);
        const char* ks_ = klb + s * 640;         // (s*8)*20*4
        #pragma unroll
        for (int j = 0; j < 8; ++j) {
            const char* xc = xs_ + j * 65536;    // uniform base per (s,j)
            const char* kc = ks_ + j * 80;
            float a = 0.f;
            #pragma unroll
            for (int tp = 0; tp < 9; ++tp) {
                float xv = *(const float*)(xc + offb[tp]);     // saddr + voffset
                float kv = *(const float*)(kc + tp * 8);       // ds_read imm offset
                a = fmaf(kv, mskf[tp] * xv, a);
            }
            a = lrelu(a);
            // truncation-based hi/lo split (exact residual)
            unsigned u  = __builtin_bit_cast(unsigned, a);
            float   hif = __builtin_bit_cast(float, u & 0xFFFF0000u);
            float   lof = a - hif;               // exact
            yhi[j] = (short)(u >> 16);
            ylo[j] = (short)(__builtin_bit_cast(unsigned, lof) >> 16);
        }
        // W fragments: per-lane voffset + scalar s*32 imm
        const char* whb = (const char*)g_whi + woffb + s * 32;
        const char* wlb = (const char*)g_wlo + woffb + s * 32;
        bfrag whi0 = *(const bfrag*)(whb);
        bfrag whi1 = *(const bfrag*)(whb + 4096);
        bfrag wlo0 = *(const bfrag*)(wlb);
        bfrag wlo1 = *(const bfrag*)(wlb + 4096);

        acc0 = __builtin_amdgcn_mfma_f32_32x32x16_bf16(whi0, yhi, acc0, 0, 0, 0);
        acc0 = __builtin_amdgcn_mfma_f32_32x32x16_bf16(whi0, ylo, acc0, 0, 0, 0);
        acc0 = __builtin_amdgcn_mfma_f32_32x32x16_bf16(wlo0, yhi, acc0, 0, 0, 0);
        acc1 = __builtin_amdgcn_mfma_f32_32x32x16_bf16(whi1, yhi, acc1, 0, 0, 0);
        acc1 = __builtin_amdgcn_mfma_f32_32x32x16_bf16(whi1, ylo, acc1, 0, 0, 0);
        acc1 = __builtin_amdgcn_mfma_f32_32x32x16_bf16(wlo1, yhi, acc1, 0, 0, 0);
    }

    // epilogue: D layout col=lane&31, row=(reg&3)+8*(reg>>2)+4*(lane>>5)
    float* ob = out + ((size_t)b << 20) + gy * HW + px;
    #pragma unroll
    for (int q = 0; q < 4; ++q) {
        const int obase = 8 * q + 4 * g;
        float4 b0 = *(const float4*)&conv_b[obase];
        float4 b1 = *(const float4*)&conv_b[32 + obase];
        const float* b0f = (const float*)&b0;
        const float* b1f = (const float*)&b1;
        #pragma unroll
        for (int rr = 0; rr < 4; ++rr) {
            ob[(size_t)(obase + rr) * 16384]      = acc0[q * 4 + rr] + b0f[rr];
            ob[(size_t)(32 + obase + rr) * 16384] = acc1[q * 4 + rr] + b1f[rr];
        }
    }
}

extern "C" void kernel_launch(void* const* d_in, const int* in_sizes, int n_in,
                              void* d_out, int out_size, void* d_ws, size_t ws_size,
                              hipStream_t stream) {
    const float* x0     = (const float*)d_in[0];
    const float* v      = (const float*)d_in[1];
    const float* ca_w1  = (const float*)d_in[2];
    const float* ca_w2  = (const float*)d_in[3];
    const float* k_w1   = (const float*)d_in[4];
    const float* k_w2   = (const float*)d_in[5];
    const float* conv_w = (const float*)d_in[6];
    const float* conv_b = (const float*)d_in[7];
    float* outp = (float*)d_out;

    dgfem_prep<<<dim3(33), dim3(64), 0, stream>>>(v, ca_w1, ca_w2, k_w1, k_w2, conv_w);
    dgfem_main<<<dim3(4096), dim3(256), 0, stream>>>(x0, conv_b, outp);
}